// Round 1
// baseline (346.939 us; speedup 1.0000x reference)
//
#include <hip/hip_runtime.h>

// BatchHide / GridMask apply: out = feature * mask (mask broadcast over C).
// feature: [B=32, C=128, H=224, W=224] f32; mask: [B,1,H,W] f32.
// Pure memory-bound streaming op -> float4 vectorized grid-stride loop.

constexpr int BB  = 32;
constexpr int CC  = 128;
constexpr int HH  = 224;
constexpr int WW  = 224;
constexpr int HW  = HH * WW;      // 50176 (divisible by 4)
constexpr int HW4 = HW / 4;       // 12544 float4s per plane

__global__ __launch_bounds__(256) void BatchHide_88295937671575_kernel(
    const float4* __restrict__ f,
    const float4* __restrict__ m,
    float4* __restrict__ o,
    int total4) {
  int idx = blockIdx.x * blockDim.x + threadIdx.x;
  int stride = gridDim.x * blockDim.x;
  for (int v = idx; v < total4; v += stride) {
    int plane  = v / HW4;            // b*C + c  (magic-mul, const divisor)
    int within = v - plane * HW4;    // vec4 offset within plane
    int b      = plane >> 7;         // plane / C, C=128
    float4 fv = f[v];
    float4 mv = m[b * HW4 + within];
    float4 ov;
    ov.x = fv.x * mv.x;
    ov.y = fv.y * mv.y;
    ov.z = fv.z * mv.z;
    ov.w = fv.w * mv.w;
    o[v] = ov;
  }
}

extern "C" void kernel_launch(void* const* d_in, const int* in_sizes, int n_in,
                              void* d_out, int out_size, void* d_ws, size_t ws_size,
                              hipStream_t stream) {
  const float4* f = (const float4*)d_in[0];  // feature [B,C,H,W]
  const float4* m = (const float4*)d_in[1];  // mask [B,1,H,W]
  float4* o = (float4*)d_out;

  int total4 = out_size / 4;  // 205,520,896 / 4 = 51,380,224

  const int block = 256;
  // Cap grid at 8 blocks/CU * 256 CUs = 2048; grid-stride covers the rest.
  int grid = (total4 + block - 1) / block;
  if (grid > 2048) grid = 2048;

  BatchHide_88295937671575_kernel<<<grid, block, 0, stream>>>(f, m, o, total4);
}

// Round 2
// 333.594 us; speedup vs baseline: 1.0400x; 1.0400x over previous
//
#include <hip/hip_runtime.h>

// BatchHide / GridMask apply: out = feature * mask (mask broadcast over C).
// feature: [B=32, C=128, H=224, W=224] f32; mask: [B,1,H,W] f32.
//
// R2 structure: one thread per spatial float4 position (b, within).
// Mask float4 loaded ONCE into registers, reused across all 128 channels.
//  - kills the 128x mask re-read (6.4 MB mask > 4 MiB/XCD L2 caused L2/L3
//    contention in R1's per-element mask load)
//  - no per-iteration div/mod
//  - HW4 = 12544 = 196 waves exactly -> every wave fully inside one plane,
//    perfectly coalesced 1 KB/instruction.

constexpr int CC  = 128;
constexpr int HH  = 224;
constexpr int WW  = 224;
constexpr int HW  = HH * WW;      // 50176
constexpr int HW4 = HW / 4;       // 12544 float4s per plane

__global__ __launch_bounds__(256) void BatchHide_88295937671575_kernel(
    const float4* __restrict__ f,
    const float4* __restrict__ m,
    float4* __restrict__ o,
    int totalSpatial4) {
  int t = blockIdx.x * blockDim.x + threadIdx.x;   // b*HW4 + within
  if (t >= totalSpatial4) return;

  int b = t / HW4;                 // const divisor -> magic mul, once per thread
  float4 mv = m[t];                // mask is [B][HW4]: index == t

  size_t base = (size_t)b * CC * HW4 + (size_t)(t - b * HW4);
  const float4* fp = f + base;
  float4*       op = o + base;

#pragma unroll 8
  for (int c = 0; c < CC; ++c) {
    float4 fv = fp[(size_t)c * HW4];
    float4 ov;
    ov.x = fv.x * mv.x;
    ov.y = fv.y * mv.y;
    ov.z = fv.z * mv.z;
    ov.w = fv.w * mv.w;
    op[(size_t)c * HW4] = ov;
  }
}

extern "C" void kernel_launch(void* const* d_in, const int* in_sizes, int n_in,
                              void* d_out, int out_size, void* d_ws, size_t ws_size,
                              hipStream_t stream) {
  const float4* f = (const float4*)d_in[0];  // feature [B,C,H,W]
  const float4* m = (const float4*)d_in[1];  // mask [B,1,H,W]
  float4* o = (float4*)d_out;

  int totalSpatial4 = (in_sizes[1] & ~3) / 4;  // B*HW/4 = 401408
  const int block = 256;
  int grid = (totalSpatial4 + block - 1) / block;  // 1568

  BatchHide_88295937671575_kernel<<<grid, block, 0, stream>>>(f, m, o, totalSpatial4);
}

// Round 4
// 270.229 us; speedup vs baseline: 1.2839x; 1.2345x over previous
//
#include <hip/hip_runtime.h>

// BatchHide / GridMask apply: out = feature * mask (mask broadcast over C).
// feature: [B=32, C=128, H=224, W=224] f32; mask: [B,1,H,W] f32.
//
// R4 = R3 with clang-native vec4 type (nontemporal builtins reject the
// HIP_vector_type struct; they need a true vector type).
//
// Structure: one thread per (b, channel-octet, spatial float4).
//  - 25088 blocks (~98/CU) -> <1% tail imbalance (R2 had 6.125 blocks/CU).
//  - mask vec4 register-cached, reused 8x.
//  - feature/out are pure streams (zero reuse) -> nontemporal load/store so
//    L2 keeps the mask instead of dead stream lines.

typedef float f32x4 __attribute__((ext_vector_type(4)));

constexpr int CC  = 128;
constexpr int HH  = 224;
constexpr int WW  = 224;
constexpr int HW  = HH * WW;      // 50176
constexpr int HW4 = HW / 4;       // 12544 float4s per plane
constexpr int CPT = 8;            // channels per thread
constexpr int NCG = CC / CPT;     // 16 channel-octets

__global__ __launch_bounds__(256) void BatchHide_88295937671575_kernel(
    const f32x4* __restrict__ f,
    const f32x4* __restrict__ m,
    f32x4* __restrict__ o) {
  int T = blockIdx.x * blockDim.x + threadIdx.x;  // (b*NCG + cg)*HW4 + within
  int G      = T / HW4;            // b*NCG + cg   (const-divisor magic mul)
  int within = T - G * HW4;
  int b  = G >> 4;                 // G / NCG
  int cg = G & (NCG - 1);

  f32x4 mv = m[b * HW4 + within];                  // cached (L2-resident) load

  size_t base = ((size_t)(b * CC + cg * CPT)) * HW4 + (size_t)within;
  const f32x4* fp = f + base;
  f32x4*       op = o + base;

#pragma unroll
  for (int i = 0; i < CPT; ++i) {
    f32x4 fv = __builtin_nontemporal_load(&fp[(size_t)i * HW4]);
    f32x4 ov = fv * mv;
    __builtin_nontemporal_store(ov, &op[(size_t)i * HW4]);
  }
}

extern "C" void kernel_launch(void* const* d_in, const int* in_sizes, int n_in,
                              void* d_out, int out_size, void* d_ws, size_t ws_size,
                              hipStream_t stream) {
  const f32x4* f = (const f32x4*)d_in[0];  // feature [B,C,H,W]
  const f32x4* m = (const f32x4*)d_in[1];  // mask [B,1,H,W]
  f32x4* o = (f32x4*)d_out;

  // total threads = B * NCG * HW4 = 32*16*12544 = 6,422,528 = 25088 * 256
  int totalThreads = (in_sizes[1] / 4) * NCG;
  const int block = 256;
  int grid = (totalThreads + block - 1) / block;   // 25088 exactly

  BatchHide_88295937671575_kernel<<<grid, block, 0, stream>>>(f, m, o);
}